// Round 19
// baseline (254.129 us; speedup 1.0000x reference)
//
#include <hip/hip_runtime.h>

#define NN 100000
#define NE 1600000
#define DD 64
#define NBKT 391    // buckets of 256 dst nodes (ceil(NN/256))
#define BCAP 4608   // per-bucket capacity: mean 4092, sd 64 -> +8 sigma (HW-validated)
#define BCH  4096   // edges per bin_k block
#define NBIN 391    // ceil(NE/BCH)
#define OVCAP 4096  // overflow capacity (never hit in practice)

typedef __attribute__((ext_vector_type(8))) short short8_t;
typedef __attribute__((ext_vector_type(4))) float f32x4;

__device__ __forceinline__ float fsig(float x) {
    return __fdividef(1.0f, 1.0f + __expf(-x));
}
__device__ __forceinline__ float ftanh(float x) {
    return __fdividef(2.0f, 1.0f + __expf(-2.0f * x)) - 1.0f;
}
__device__ __forceinline__ unsigned int bf16rne(float a) {
    unsigned int u = __float_as_uint(a);
    return (u + 0x7fffu + ((u >> 16) & 1u)) >> 16;
}
__device__ __forceinline__ short8_t pack8(float4 a, float4 b) {
    short8_t r;
    r[0] = (short)bf16rne(a.x); r[1] = (short)bf16rne(a.y);
    r[2] = (short)bf16rne(a.z); r[3] = (short)bf16rne(a.w);
    r[4] = (short)bf16rne(b.x); r[5] = (short)bf16rne(b.y);
    r[6] = (short)bf16rne(b.z); r[7] = (short)bf16rne(b.w);
    return r;
}

// ---- bin_k: bucket binning + folded hcvt + folded wprep -----------------
// Fusions remove 2 dispatches (~20us of gaps+overhead). hcvt: grid-stride
// bf16 mirror of h (3.2M dwords over 200K threads). wprep: first 6144
// threads pack Wih/Whh into MFMA B-frag order. Binning logic unchanged
// from the measured 218.8/222.6us runs.
__global__ __launch_bounds__(512) void bin_k(const int* __restrict__ src,
                                             const int* __restrict__ dst,
                                             const float* __restrict__ ew,
                                             const float* __restrict__ h,
                                             const float* __restrict__ Wih,
                                             const float* __restrict__ Whh,
                                             unsigned* __restrict__ hb,
                                             unsigned* __restrict__ wfrag,
                                             unsigned* __restrict__ gcnt,
                                             unsigned* __restrict__ binkey,
                                             unsigned short* __restrict__ binwgt,
                                             unsigned* __restrict__ ovcnt,
                                             unsigned* __restrict__ ov_key,
                                             unsigned short* __restrict__ ov_wgt,
                                             unsigned* __restrict__ ov_b) {
    __shared__ unsigned cnt[NBKT];
    __shared__ unsigned cur[NBKT];
    __shared__ unsigned offb[NBKT];
    __shared__ unsigned gbase[NBKT];
    __shared__ unsigned ssc[512];
    __shared__ unsigned stage_key[BCH];
    __shared__ unsigned short stage_wgt[BCH];
    __shared__ unsigned short sbkt[BCH];

    const int t = threadIdx.x;
    const int gid = blockIdx.x * 512 + t;

    // folded hcvt: bf16 mirror of h (coalesced float2 loads)
    for (int i = gid; i < NN * (DD / 2); i += NBIN * 512) {
        const float2 v = *(const float2*)(h + (size_t)i * 2);
        hb[i] = bf16rne(v.x) | (bf16rne(v.y) << 16);
    }
    // folded wprep: pack weights into MFMA B-fragment order
    if (gid < 6144) {
        const int row = gid >> 5;        // 0..191
        const int k2  = gid & 31;
        const int ct  = row >> 4;
        const int c   = row & 15;
        const int ks  = k2 >> 4;
        const int lhi = (k2 >> 2) & 3;
        const int lane = c + (lhi << 4);
        const int slot = k2 & 3;
        const int fo = (((ct << 1) + ks) << 8) + (lane << 2) + slot;
        const float2 wi = *(const float2*)(Wih + (row << 6) + (k2 << 1));
        const float2 wh = *(const float2*)(Whh + (row << 6) + (k2 << 1));
        wfrag[fo]            = bf16rne(wi.x) | (bf16rne(wi.y) << 16);
        wfrag[24 * 256 + fo] = bf16rne(wh.x) | (bf16rne(wh.y) << 16);
    }

    const int e0 = blockIdx.x * BCH;
    const int M = min(BCH, NE - e0);

    for (int i = t; i < NBKT; i += 512) cnt[i] = 0;
    __syncthreads();

    for (int i = t; i < M; i += 512) {
        const unsigned b = ((unsigned)dst[e0 + i]) >> 8;
        atomicAdd(&cnt[b], 1u);
    }
    __syncthreads();

    {
        const unsigned v = (t < NBKT) ? cnt[t] : 0u;
        ssc[t] = v;
        __syncthreads();
        for (int o = 1; o < 512; o <<= 1) {
            const unsigned tmp = (t >= o) ? ssc[t - o] : 0u;
            __syncthreads();
            ssc[t] += tmp;
            __syncthreads();
        }
        if (t < NBKT) { offb[t] = ssc[t] - v; cur[t] = ssc[t] - v; }
    }
    __syncthreads();

    for (int i = t; i < M; i += 512) {
        const int d = dst[e0 + i];
        const unsigned b = ((unsigned)d) >> 8;
        const unsigned p = atomicAdd(&cur[b], 1u);
        stage_key[p] = (unsigned)src[e0 + i] | (((unsigned)(d & 255)) << 17);
        stage_wgt[p] = (unsigned short)bf16rne(ew[e0 + i]);
        sbkt[p] = (unsigned short)b;
    }
    __syncthreads();

    for (int i = t; i < NBKT; i += 512) {
        const unsigned c = cnt[i];
        gbase[i] = c ? atomicAdd(&gcnt[i], c) : 0u;
    }
    __syncthreads();

    for (int i = t; i < M; i += 512) {
        const unsigned b = sbkt[i];
        const unsigned gp = gbase[b] + ((unsigned)i - offb[b]);
        if (gp < BCAP) {
            binkey[b * BCAP + gp] = stage_key[i];
            binwgt[b * BCAP + gp] = stage_wgt[i];
        } else {                                    // ~never: +8 sigma margin
            const unsigned op = atomicAdd(ovcnt, 1u);
            if (op < OVCAP) {
                ov_key[op] = stage_key[i];
                ov_wgt[op] = stage_wgt[i];
                ov_b[op] = b;
            }
        }
    }
}

// ---- sort_k: in-place exact sort within each bucket + CSR emit ----------
// (Unchanged from the measured runs.)
__global__ __launch_bounds__(512) void sort_k(unsigned* __restrict__ binkey,
                                              unsigned short* __restrict__ binwgt,
                                              const unsigned* __restrict__ gcnt,
                                              const unsigned* __restrict__ ovcnt,
                                              const unsigned* __restrict__ ov_key,
                                              const unsigned short* __restrict__ ov_wgt,
                                              const unsigned* __restrict__ ov_b,
                                              unsigned* __restrict__ cursor,
                                              unsigned* __restrict__ deg) {
    __shared__ unsigned hcnt[256];
    __shared__ unsigned off[256];
    __shared__ unsigned cur[256];
    __shared__ unsigned ssc[256];
    __shared__ unsigned stage_key[BCAP];        // 18,432 B
    __shared__ unsigned short stage_wgt[BCAP];  //  9,216 B

    const int t = threadIdx.x;
    const int b = blockIdx.x;
    const unsigned base = (unsigned)b * BCAP;
    const unsigned cnt = min(gcnt[b], (unsigned)BCAP);
    const unsigned oc = min(*ovcnt, (unsigned)OVCAP);

    if (t < 256) hcnt[t] = 0;
    __syncthreads();

    for (unsigned i = t; i < cnt; i += 512)
        atomicAdd(&hcnt[binkey[base + i] >> 17], 1u);
    for (unsigned i = t; i < oc; i += 512)
        if (ov_b[i] == (unsigned)b) atomicAdd(&hcnt[ov_key[i] >> 17], 1u);
    __syncthreads();

    unsigned v = 0;
    if (t < 256) { v = hcnt[t]; ssc[t] = v; }
    __syncthreads();
    for (int o = 1; o < 256; o <<= 1) {
        unsigned tmp = 0;
        if (t < 256 && t >= o) tmp = ssc[t - o];
        __syncthreads();
        if (t < 256) ssc[t] += tmp;
        __syncthreads();
    }
    if (t < 256) { off[t] = ssc[t] - v; cur[t] = ssc[t] - v; }
    __syncthreads();

    const int nb = min(256, NN - b * 256);
    if (t < nb) {
        const int node = b * 256 + t;
        deg[node] = hcnt[t];
        cursor[node] = base + off[t] + hcnt[t];
    }

    for (unsigned i = t; i < cnt; i += 512) {
        const unsigned k = binkey[base + i];
        const unsigned short w = binwgt[base + i];
        const unsigned p = atomicAdd(&cur[k >> 17], 1u);
        if (p < (unsigned)BCAP) { stage_key[p] = k; stage_wgt[p] = w; }
    }
    for (unsigned i = t; i < oc; i += 512) {
        if (ov_b[i] == (unsigned)b) {
            const unsigned k = ov_key[i];
            const unsigned p = atomicAdd(&cur[k >> 17], 1u);
            if (p < (unsigned)BCAP) { stage_key[p] = k; stage_wgt[p] = ov_wgt[i]; }
        }
    }
    __syncthreads();

    const unsigned tot = min(ssc[255], (unsigned)BCAP);
    for (unsigned i = t; i < tot; i += 512) {
        binkey[base + i] = stage_key[i];
        binwgt[base + i] = stage_wgt[i];
    }
}

// ---- seggru_k: fused segment-sum + GRU ----------------------------------
// 1024 threads = 16 waves = 16 nodes = one GRU group. Phase 1: each wave
// runs the measured bf16-gather segsum for its node, parking hnew in LDS
// (pad 68 -> 2-way aliasing only, free per m136). Phase 2: waves 0-3 run
// the GRU; wave w owns coltiles ct={w,w+4,w+8} (= r/z/n slices of channels
// 16w..16w+15) so the epilogue is self-contained. hnew never touches HBM
// (saves 51MB round trip + a dispatch gap).
__global__ __launch_bounds__(1024) void seggru_k(const unsigned* __restrict__ hb,
                                                 const unsigned* __restrict__ binkey,
                                                 const unsigned short* __restrict__ binwgt,
                                                 const unsigned* __restrict__ cursor,
                                                 const unsigned* __restrict__ deg,
                                                 const float* __restrict__ h,
                                                 const unsigned* __restrict__ wfrag,
                                                 const float* __restrict__ bih,
                                                 const float* __restrict__ bhh,
                                                 float* __restrict__ out) {
    __shared__ float xnew[16][68];   // pad 68 -> 2-way LDS aliasing on gru reads

    const int tid = threadIdx.x;
    const int wid = tid >> 6;            // 0..15
    const int lane = tid & 63;
    const int nbase = blockIdx.x << 4;   // 6250*16 == NN exactly
    const int node = nbase + wid;

    // ---- phase 1: segsum for this wave's node (measured r16 inner loop) --
    {
        const unsigned end = cursor[node];
        const unsigned len = deg[node];
        const unsigned start = end - len;
        const unsigned g = (unsigned)(lane >> 4);   // edge slot 0..3
        const int c2 = (lane & 15) << 1;            // dword offset in row

        float4 acc  = make_float4(0.f, 0.f, 0.f, 0.f);
        float4 acc2 = make_float4(0.f, 0.f, 0.f, 0.f);
        for (unsigned base = start; base < end; base += 8) {
            const unsigned e0 = base + g;
            const unsigned e1 = base + 4 + g;
            if (e0 < end) {
                const unsigned k = binkey[e0];
                const float w = __uint_as_float(((unsigned)binwgt[e0]) << 16);
                const uint2 u = *(const uint2*)(hb + (((size_t)(k & 0x1ffffu)) << 5) + c2);
                acc.x = fmaf(w, __uint_as_float(u.x << 16),          acc.x);
                acc.y = fmaf(w, __uint_as_float(u.x & 0xffff0000u),  acc.y);
                acc.z = fmaf(w, __uint_as_float(u.y << 16),          acc.z);
                acc.w = fmaf(w, __uint_as_float(u.y & 0xffff0000u),  acc.w);
            }
            if (e1 < end) {
                const unsigned k = binkey[e1];
                const float w = __uint_as_float(((unsigned)binwgt[e1]) << 16);
                const uint2 u = *(const uint2*)(hb + (((size_t)(k & 0x1ffffu)) << 5) + c2);
                acc2.x = fmaf(w, __uint_as_float(u.x << 16),          acc2.x);
                acc2.y = fmaf(w, __uint_as_float(u.x & 0xffff0000u),  acc2.y);
                acc2.z = fmaf(w, __uint_as_float(u.y << 16),          acc2.z);
                acc2.w = fmaf(w, __uint_as_float(u.y & 0xffff0000u),  acc2.w);
            }
        }
        acc.x += acc2.x; acc.y += acc2.y; acc.z += acc2.z; acc.w += acc2.w;
        #pragma unroll
        for (int off = 16; off < 64; off <<= 1) {
            acc.x += __shfl_xor(acc.x, off);
            acc.y += __shfl_xor(acc.y, off);
            acc.z += __shfl_xor(acc.z, off);
            acc.w += __shfl_xor(acc.w, off);
        }
        if (lane < 16) *(float4*)(&xnew[wid][lane << 2]) = acc;
    }
    __syncthreads();
    if (wid >= 4) return;

    // ---- phase 2: GRU, wave wid owns coltiles {wid, wid+4, wid+8} --------
    const int rA   = lane & 15;
    const int koff = (lane >> 4) << 3;
    const float* hr = h + ((size_t)(nbase + rA) << 6);

    short8_t ax[2], ah[2];
    #pragma unroll
    for (int ks = 0; ks < 2; ++ks) {
        const float4 x0 = *(const float4*)(&xnew[rA][ks * 32 + koff]);
        const float4 x1 = *(const float4*)(&xnew[rA][ks * 32 + koff + 4]);
        const float4 h0 = *(const float4*)(hr + ks * 32 + koff);
        const float4 h1 = *(const float4*)(hr + ks * 32 + koff + 4);
        ax[ks] = pack8(x0, x1);
        ah[ks] = pack8(h0, h1);
    }

    f32x4 accI[3], accH[3];
    #pragma unroll
    for (int j = 0; j < 3; ++j) {
        accI[j] = (f32x4){0.f, 0.f, 0.f, 0.f};
        accH[j] = (f32x4){0.f, 0.f, 0.f, 0.f};
    }

    const unsigned* wf = wfrag + (lane << 2);
    #pragma unroll
    for (int j = 0; j < 3; ++j) {
        const int ct = wid + 4 * j;
        const short8_t b0 = *(const short8_t*)(wf + (((ct << 1)     ) << 8));
        const short8_t b1 = *(const short8_t*)(wf + (((ct << 1) + 1) << 8));
        const short8_t c0 = *(const short8_t*)(wf + ((24 + (ct << 1)    ) << 8));
        const short8_t c1 = *(const short8_t*)(wf + ((24 + (ct << 1) + 1) << 8));
        accI[j] = __builtin_amdgcn_mfma_f32_16x16x32_bf16(ax[0], b0, accI[j], 0, 0, 0);
        accI[j] = __builtin_amdgcn_mfma_f32_16x16x32_bf16(ax[1], b1, accI[j], 0, 0, 0);
        accH[j] = __builtin_amdgcn_mfma_f32_16x16x32_bf16(ah[0], c0, accH[j], 0, 0, 0);
        accH[j] = __builtin_amdgcn_mfma_f32_16x16x32_bf16(ah[1], c1, accH[j], 0, 0, 0);
    }

    // epilogue: C layout (m89) col = lane&15, row = 4*(lane>>4) + reg
    const int c  = lane & 15;
    const int ch = (wid << 4) + c;
    const float brz = bih[ch] + bhh[ch];
    const float bzz = bih[64 + ch] + bhh[64 + ch];
    const float bin_ = bih[128 + ch];
    const float bhn = bhh[128 + ch];
    const int rnode = nbase + ((lane >> 4) << 2);
    #pragma unroll
    for (int r = 0; r < 4; ++r) {
        const int node2 = rnode + r;
        const float rr = fsig(accI[0][r] + accH[0][r] + brz);
        const float zz = fsig(accI[1][r] + accH[1][r] + bzz);
        const float hn = accH[2][r] + bhn;
        const float nn = ftanh(fmaf(rr, hn, accI[2][r] + bin_));
        const float hv = h[((size_t)node2 << 6) + ch];
        out[((size_t)node2 << 6) + ch] = fmaf(zz, hv - nn, nn);  // (1-z)*n + z*h
    }
}

extern "C" void kernel_launch(void* const* d_in, const int* in_sizes, int n_in,
                              void* d_out, int out_size, void* d_ws, size_t ws_size,
                              hipStream_t stream)
{
    const float* h   = (const float*)d_in[0];
    const float* ew  = (const float*)d_in[1];
    const float* Wih = (const float*)d_in[2];
    const float* Whh = (const float*)d_in[3];
    const float* bih = (const float*)d_in[4];
    const float* bhh = (const float*)d_in[5];
    const int*   src = (const int*)d_in[6];
    const int*   dst = (const int*)d_in[7];
    float* out = (float*)d_out;

    // ws layout (~23.4 MB, under the 25.6 MB proven available)
    char* ws = (char*)d_ws;
    unsigned*       gcnt   = (unsigned*)      (ws);              //   2,048 B
    unsigned*       ovcnt  = (unsigned*)      (ws + 2048);       //      64 B
    unsigned*       wfrag  = (unsigned*)      (ws + 2112);       //  49,152 B
    unsigned*       binkey = (unsigned*)      (ws + 65536);      // 7,206,912 B
    unsigned short* binwgt = (unsigned short*)(ws + 7272448);    // 3,603,456 B
    unsigned*       ov_key = (unsigned*)      (ws + 10875904);   //  16,384 B
    unsigned short* ov_wgt = (unsigned short*)(ws + 10892288);   //   8,192 B
    unsigned*       ov_b   = (unsigned*)      (ws + 10900480);   //  16,384 B
    unsigned*       deg    = (unsigned*)      (ws + 10916864);   // 400,000 B
    unsigned*       cursor = (unsigned*)      (ws + 11316864);   // 400,000 B
    unsigned*       hb     = (unsigned*)      (ws + 11716864);   // 12,800,000 B -> 24,516,864

    hipMemsetAsync(ws, 0, 2112, stream);                    // gcnt + ovcnt
    bin_k  <<<NBIN, 512, 0, stream>>>(src, dst, ew, h, Wih, Whh, hb, wfrag,
                                      gcnt, binkey, binwgt,
                                      ovcnt, ov_key, ov_wgt, ov_b);
    sort_k <<<NBKT, 512, 0, stream>>>(binkey, binwgt, gcnt, ovcnt,
                                      ov_key, ov_wgt, ov_b, cursor, deg);
    seggru_k<<<NN / 16, 1024, 0, stream>>>(hb, binkey, binwgt, cursor, deg,
                                           h, wfrag, bih, bhh, out);
}

// Round 21
// 199.621 us; speedup vs baseline: 1.2731x; 1.2731x over previous
//
#include <hip/hip_runtime.h>

#define NN 100000
#define NE 1600000
#define DD 64
#define NGRP 6250   // NN/16
#define NBGRU 1563  // ceil(NGRP/4)
#define NBKT 391    // buckets of 256 dst nodes (ceil(NN/256))
#define BCAP 4608   // per-bucket capacity: mean 4092, sd 64 -> +8 sigma (HW-validated)
#define BCH  4096   // edges per bin_k block
#define NBIN 391    // ceil(NE/BCH)
#define OVCAP 4096  // overflow capacity (never hit in practice)

typedef __attribute__((ext_vector_type(8))) short short8_t;
typedef __attribute__((ext_vector_type(4))) float f32x4;

__device__ __forceinline__ float fsig(float x) {
    return __fdividef(1.0f, 1.0f + __expf(-x));
}
__device__ __forceinline__ float ftanh(float x) {
    return __fdividef(2.0f, 1.0f + __expf(-2.0f * x)) - 1.0f;
}
__device__ __forceinline__ unsigned int bf16rne(float a) {
    unsigned int u = __float_as_uint(a);
    return (u + 0x7fffu + ((u >> 16) & 1u)) >> 16;
}
__device__ __forceinline__ float bflo(unsigned u) { return __uint_as_float(u << 16); }
__device__ __forceinline__ float bfhi(unsigned u) { return __uint_as_float(u & 0xffff0000u); }
__device__ __forceinline__ short8_t pack8(float4 a, float4 b) {
    short8_t r;
    r[0] = (short)bf16rne(a.x); r[1] = (short)bf16rne(a.y);
    r[2] = (short)bf16rne(a.z); r[3] = (short)bf16rne(a.w);
    r[4] = (short)bf16rne(b.x); r[5] = (short)bf16rne(b.y);
    r[6] = (short)bf16rne(b.z); r[7] = (short)bf16rne(b.w);
    return r;
}

// ---- bin_k: bucket binning + folded hcvt + folded wprep -----------------
// (r19 verified this fold passes; seggru fusion was the regression and is
// reverted. Binning logic unchanged from the measured 218.8/222.6us runs.)
__global__ __launch_bounds__(512) void bin_k(const int* __restrict__ src,
                                             const int* __restrict__ dst,
                                             const float* __restrict__ ew,
                                             const float* __restrict__ h,
                                             const float* __restrict__ Wih,
                                             const float* __restrict__ Whh,
                                             unsigned* __restrict__ hb,
                                             unsigned* __restrict__ wfrag,
                                             unsigned* __restrict__ gcnt,
                                             unsigned* __restrict__ binkey,
                                             unsigned short* __restrict__ binwgt,
                                             unsigned* __restrict__ ovcnt,
                                             unsigned* __restrict__ ov_key,
                                             unsigned short* __restrict__ ov_wgt,
                                             unsigned* __restrict__ ov_b) {
    __shared__ unsigned cnt[NBKT];
    __shared__ unsigned cur[NBKT];
    __shared__ unsigned offb[NBKT];
    __shared__ unsigned gbase[NBKT];
    __shared__ unsigned ssc[512];
    __shared__ unsigned stage_key[BCH];
    __shared__ unsigned short stage_wgt[BCH];
    __shared__ unsigned short sbkt[BCH];

    const int t = threadIdx.x;
    const int gid = blockIdx.x * 512 + t;

    // folded hcvt: bf16 mirror of h (coalesced float2 loads)
    for (int i = gid; i < NN * (DD / 2); i += NBIN * 512) {
        const float2 v = *(const float2*)(h + (size_t)i * 2);
        hb[i] = bf16rne(v.x) | (bf16rne(v.y) << 16);
    }
    // folded wprep: pack weights into MFMA B-fragment order
    if (gid < 6144) {
        const int row = gid >> 5;        // 0..191
        const int k2  = gid & 31;
        const int ct  = row >> 4;
        const int c   = row & 15;
        const int ks  = k2 >> 4;
        const int lhi = (k2 >> 2) & 3;
        const int lane = c + (lhi << 4);
        const int slot = k2 & 3;
        const int fo = (((ct << 1) + ks) << 8) + (lane << 2) + slot;
        const float2 wi = *(const float2*)(Wih + (row << 6) + (k2 << 1));
        const float2 wh = *(const float2*)(Whh + (row << 6) + (k2 << 1));
        wfrag[fo]            = bf16rne(wi.x) | (bf16rne(wi.y) << 16);
        wfrag[24 * 256 + fo] = bf16rne(wh.x) | (bf16rne(wh.y) << 16);
    }

    const int e0 = blockIdx.x * BCH;
    const int M = min(BCH, NE - e0);

    for (int i = t; i < NBKT; i += 512) cnt[i] = 0;
    __syncthreads();

    for (int i = t; i < M; i += 512) {
        const unsigned b = ((unsigned)dst[e0 + i]) >> 8;
        atomicAdd(&cnt[b], 1u);
    }
    __syncthreads();

    {
        const unsigned v = (t < NBKT) ? cnt[t] : 0u;
        ssc[t] = v;
        __syncthreads();
        for (int o = 1; o < 512; o <<= 1) {
            const unsigned tmp = (t >= o) ? ssc[t - o] : 0u;
            __syncthreads();
            ssc[t] += tmp;
            __syncthreads();
        }
        if (t < NBKT) { offb[t] = ssc[t] - v; cur[t] = ssc[t] - v; }
    }
    __syncthreads();

    for (int i = t; i < M; i += 512) {
        const int d = dst[e0 + i];
        const unsigned b = ((unsigned)d) >> 8;
        const unsigned p = atomicAdd(&cur[b], 1u);
        stage_key[p] = (unsigned)src[e0 + i] | (((unsigned)(d & 255)) << 17);
        stage_wgt[p] = (unsigned short)bf16rne(ew[e0 + i]);
        sbkt[p] = (unsigned short)b;
    }
    __syncthreads();

    for (int i = t; i < NBKT; i += 512) {
        const unsigned c = cnt[i];
        gbase[i] = c ? atomicAdd(&gcnt[i], c) : 0u;
    }
    __syncthreads();

    for (int i = t; i < M; i += 512) {
        const unsigned b = sbkt[i];
        const unsigned gp = gbase[b] + ((unsigned)i - offb[b]);
        if (gp < BCAP) {
            binkey[b * BCAP + gp] = stage_key[i];
            binwgt[b * BCAP + gp] = stage_wgt[i];
        } else {                                    // ~never: +8 sigma margin
            const unsigned op = atomicAdd(ovcnt, 1u);
            if (op < OVCAP) {
                ov_key[op] = stage_key[i];
                ov_wgt[op] = stage_wgt[i];
                ov_b[op] = b;
            }
        }
    }
}

// ---- sort_k: in-place exact sort within each bucket + CSR emit ----------
// (Unchanged from the measured runs.)
__global__ __launch_bounds__(512) void sort_k(unsigned* __restrict__ binkey,
                                              unsigned short* __restrict__ binwgt,
                                              const unsigned* __restrict__ gcnt,
                                              const unsigned* __restrict__ ovcnt,
                                              const unsigned* __restrict__ ov_key,
                                              const unsigned short* __restrict__ ov_wgt,
                                              const unsigned* __restrict__ ov_b,
                                              unsigned* __restrict__ cursor,
                                              unsigned* __restrict__ deg) {
    __shared__ unsigned hcnt[256];
    __shared__ unsigned off[256];
    __shared__ unsigned cur[256];
    __shared__ unsigned ssc[256];
    __shared__ unsigned stage_key[BCAP];        // 18,432 B
    __shared__ unsigned short stage_wgt[BCAP];  //  9,216 B

    const int t = threadIdx.x;
    const int b = blockIdx.x;
    const unsigned base = (unsigned)b * BCAP;
    const unsigned cnt = min(gcnt[b], (unsigned)BCAP);
    const unsigned oc = min(*ovcnt, (unsigned)OVCAP);

    if (t < 256) hcnt[t] = 0;
    __syncthreads();

    for (unsigned i = t; i < cnt; i += 512)
        atomicAdd(&hcnt[binkey[base + i] >> 17], 1u);
    for (unsigned i = t; i < oc; i += 512)
        if (ov_b[i] == (unsigned)b) atomicAdd(&hcnt[ov_key[i] >> 17], 1u);
    __syncthreads();

    unsigned v = 0;
    if (t < 256) { v = hcnt[t]; ssc[t] = v; }
    __syncthreads();
    for (int o = 1; o < 256; o <<= 1) {
        unsigned tmp = 0;
        if (t < 256 && t >= o) tmp = ssc[t - o];
        __syncthreads();
        if (t < 256) ssc[t] += tmp;
        __syncthreads();
    }
    if (t < 256) { off[t] = ssc[t] - v; cur[t] = ssc[t] - v; }
    __syncthreads();

    const int nb = min(256, NN - b * 256);
    if (t < nb) {
        const int node = b * 256 + t;
        deg[node] = hcnt[t];
        cursor[node] = base + off[t] + hcnt[t];
    }

    for (unsigned i = t; i < cnt; i += 512) {
        const unsigned k = binkey[base + i];
        const unsigned short w = binwgt[base + i];
        const unsigned p = atomicAdd(&cur[k >> 17], 1u);
        if (p < (unsigned)BCAP) { stage_key[p] = k; stage_wgt[p] = w; }
    }
    for (unsigned i = t; i < oc; i += 512) {
        if (ov_b[i] == (unsigned)b) {
            const unsigned k = ov_key[i];
            const unsigned p = atomicAdd(&cur[k >> 17], 1u);
            if (p < (unsigned)BCAP) { stage_key[p] = k; stage_wgt[p] = ov_wgt[i]; }
        }
    }
    __syncthreads();

    const unsigned tot = min(ssc[255], (unsigned)BCAP);
    for (unsigned i = t; i < tot; i += 512) {
        binkey[base + i] = stage_key[i];
        binwgt[base + i] = stage_wgt[i];
    }
}

// ---- Segment sum, 16 edges in flight per wave ---------------------------
// r16 measured: bf16 gathers at 59us, 87MB/59us = 1.5 TB/s beyond-L2 --
// NOT at the ~3 TB/s ceiling the f32 version saturated -> latency-bound
// again in this regime (r13's MLP-null was measured in the saturated f32
// regime and doesn't transfer). Now: lane l -> edge slot g=l>>3 (8 slots,
// 2 groups, step 16), 8 channels/lane via one uint4 (16B) load per edge.
// 16 outstanding 128B row-requests/wave (was 8), ~half the VALU per edge.
__global__ __launch_bounds__(256) void segsum_k(const unsigned* __restrict__ hb,
                                                const unsigned* __restrict__ binkey,
                                                const unsigned short* __restrict__ binwgt,
                                                const unsigned* __restrict__ cursor,
                                                const unsigned* __restrict__ deg,
                                                float* __restrict__ hnew) {
    const int node = blockIdx.x * 4 + (threadIdx.x >> 6);   // 25000*4 == NN
    const int lane = threadIdx.x & 63;
    const unsigned end = cursor[node];
    const unsigned len = deg[node];
    const unsigned start = end - len;
    const unsigned g = (unsigned)(lane >> 3);   // edge slot 0..7
    const int c4 = (lane & 7) << 2;             // dword base in row (8 ch/lane)

    float4 a0 = make_float4(0.f, 0.f, 0.f, 0.f);
    float4 a1 = make_float4(0.f, 0.f, 0.f, 0.f);
    float4 b0 = make_float4(0.f, 0.f, 0.f, 0.f);
    float4 b1 = make_float4(0.f, 0.f, 0.f, 0.f);
    for (unsigned base = start; base < end; base += 16) {
        const unsigned e0 = base + g;
        const unsigned e1 = base + 8 + g;
        if (e0 < end) {
            const unsigned k = binkey[e0];                  // 8-lane broadcast
            const float w = __uint_as_float(((unsigned)binwgt[e0]) << 16);
            const uint4 u = *(const uint4*)(hb + (((size_t)(k & 0x1ffffu)) << 5) + c4);
            a0.x = fmaf(w, bflo(u.x), a0.x); a0.y = fmaf(w, bfhi(u.x), a0.y);
            a0.z = fmaf(w, bflo(u.y), a0.z); a0.w = fmaf(w, bfhi(u.y), a0.w);
            a1.x = fmaf(w, bflo(u.z), a1.x); a1.y = fmaf(w, bfhi(u.z), a1.y);
            a1.z = fmaf(w, bflo(u.w), a1.z); a1.w = fmaf(w, bfhi(u.w), a1.w);
        }
        if (e1 < end) {
            const unsigned k = binkey[e1];
            const float w = __uint_as_float(((unsigned)binwgt[e1]) << 16);
            const uint4 u = *(const uint4*)(hb + (((size_t)(k & 0x1ffffu)) << 5) + c4);
            b0.x = fmaf(w, bflo(u.x), b0.x); b0.y = fmaf(w, bfhi(u.x), b0.y);
            b0.z = fmaf(w, bflo(u.y), b0.z); b0.w = fmaf(w, bfhi(u.y), b0.w);
            b1.x = fmaf(w, bflo(u.z), b1.x); b1.y = fmaf(w, bfhi(u.z), b1.y);
            b1.z = fmaf(w, bflo(u.w), b1.z); b1.w = fmaf(w, bfhi(u.w), b1.w);
        }
    }
    a0.x += b0.x; a0.y += b0.y; a0.z += b0.z; a0.w += b0.w;
    a1.x += b1.x; a1.y += b1.y; a1.z += b1.z; a1.w += b1.w;
    // reduce over edge-slot bits (lane bits 3,4,5)
    #pragma unroll
    for (int off = 8; off < 64; off <<= 1) {
        a0.x += __shfl_xor(a0.x, off); a0.y += __shfl_xor(a0.y, off);
        a0.z += __shfl_xor(a0.z, off); a0.w += __shfl_xor(a0.w, off);
        a1.x += __shfl_xor(a1.x, off); a1.y += __shfl_xor(a1.y, off);
        a1.z += __shfl_xor(a1.z, off); a1.w += __shfl_xor(a1.w, off);
    }
    if (lane < 8) {
        float* dstp = hnew + ((size_t)node << 6) + (lane << 3);
        *(float4*)(dstp)     = a0;
        *(float4*)(dstp + 4) = a1;
    }
}

// ---- GRU cell via MFMA (measured-good since r2; never in top-5) ---------
// One wave per 16-node group; 96 mfma_f32_16x16x32_bf16 per wave; no LDS.
// C layout (m89): col = lane&15, row = 4*(lane>>4) + reg.
__global__ __launch_bounds__(256) void gru_k(
    const float* hnew, const float* __restrict__ h,
    const unsigned* __restrict__ wfrag,
    const float* __restrict__ bih, const float* __restrict__ bhh,
    float* out)
{
    const int tid  = threadIdx.x;
    const int wid  = tid >> 6;
    const int lane = tid & 63;
    const int grp  = blockIdx.x * 4 + wid;
    if (grp >= NGRP) return;
    const int base = grp << 4;

    const int rA   = lane & 15;
    const int koff = (lane >> 4) << 3;

    const float* xr = hnew + ((base + rA) << 6);
    const float* hr = h    + ((base + rA) << 6);

    short8_t ax[2], ah[2];
    #pragma unroll
    for (int ks = 0; ks < 2; ++ks) {
        const float4 x0 = *(const float4*)(xr + ks * 32 + koff);
        const float4 x1 = *(const float4*)(xr + ks * 32 + koff + 4);
        const float4 h0 = *(const float4*)(hr + ks * 32 + koff);
        const float4 h1 = *(const float4*)(hr + ks * 32 + koff + 4);
        ax[ks] = pack8(x0, x1);
        ah[ks] = pack8(h0, h1);
    }

    f32x4 acc[24];
    #pragma unroll
    for (int i = 0; i < 24; ++i) acc[i] = (f32x4){0.f, 0.f, 0.f, 0.f};

    const unsigned* wf = wfrag + (lane << 2);
    #pragma unroll
    for (int ct = 0; ct < 12; ++ct) {
        const short8_t b0 = *(const short8_t*)(wf + (((ct << 1)     ) << 8));
        const short8_t b1 = *(const short8_t*)(wf + (((ct << 1) + 1) << 8));
        const short8_t c0 = *(const short8_t*)(wf + ((24 + (ct << 1)    ) << 8));
        const short8_t c1 = *(const short8_t*)(wf + ((24 + (ct << 1) + 1) << 8));
        acc[ct]      = __builtin_amdgcn_mfma_f32_16x16x32_bf16(ax[0], b0, acc[ct],      0, 0, 0);
        acc[ct]      = __builtin_amdgcn_mfma_f32_16x16x32_bf16(ax[1], b1, acc[ct],      0, 0, 0);
        acc[12 + ct] = __builtin_amdgcn_mfma_f32_16x16x32_bf16(ah[0], c0, acc[12 + ct], 0, 0, 0);
        acc[12 + ct] = __builtin_amdgcn_mfma_f32_16x16x32_bf16(ah[1], c1, acc[12 + ct], 0, 0, 0);
    }

    const int rnode = base + ((lane >> 4) << 2);
    const int c     = lane & 15;
    #pragma unroll
    for (int ct = 0; ct < 4; ++ct) {
        const int ch = (ct << 4) + c;
        const float brz = bih[ch] + bhh[ch];
        const float bzz = bih[64 + ch] + bhh[64 + ch];
        const float bin = bih[128 + ch];
        const float bhn = bhh[128 + ch];
        #pragma unroll
        for (int r = 0; r < 4; ++r) {
            const int node = rnode + r;
            const float rr = fsig(acc[ct][r] + acc[12 + ct][r] + brz);
            const float zz = fsig(acc[4 + ct][r] + acc[16 + ct][r] + bzz);
            const float hn = acc[20 + ct][r] + bhn;
            const float nn = ftanh(fmaf(rr, hn, acc[8 + ct][r] + bin));
            const float hv = h[(node << 6) + ch];
            out[(node << 6) + ch] = fmaf(zz, hv - nn, nn);  // (1-z)*n + z*h
        }
    }
}

extern "C" void kernel_launch(void* const* d_in, const int* in_sizes, int n_in,
                              void* d_out, int out_size, void* d_ws, size_t ws_size,
                              hipStream_t stream)
{
    const float* h   = (const float*)d_in[0];
    const float* ew  = (const float*)d_in[1];
    const float* Wih = (const float*)d_in[2];
    const float* Whh = (const float*)d_in[3];
    const float* bih = (const float*)d_in[4];
    const float* bhh = (const float*)d_in[5];
    const int*   src = (const int*)d_in[6];
    const int*   dst = (const int*)d_in[7];
    float* out = (float*)d_out;

    // ws layout (~23.4 MB, under the 25.6 MB proven available)
    char* ws = (char*)d_ws;
    unsigned*       gcnt   = (unsigned*)      (ws);              //   2,048 B
    unsigned*       ovcnt  = (unsigned*)      (ws + 2048);       //      64 B
    unsigned*       wfrag  = (unsigned*)      (ws + 2112);       //  49,152 B
    unsigned*       binkey = (unsigned*)      (ws + 65536);      // 7,206,912 B
    unsigned short* binwgt = (unsigned short*)(ws + 7272448);    // 3,603,456 B
    unsigned*       ov_key = (unsigned*)      (ws + 10875904);   //  16,384 B
    unsigned short* ov_wgt = (unsigned short*)(ws + 10892288);   //   8,192 B
    unsigned*       ov_b   = (unsigned*)      (ws + 10900480);   //  16,384 B
    unsigned*       deg    = (unsigned*)      (ws + 10916864);   // 400,000 B
    unsigned*       cursor = (unsigned*)      (ws + 11316864);   // 400,000 B
    unsigned*       hb     = (unsigned*)      (ws + 11716864);   // 12,800,000 B -> 24,516,864

    hipMemsetAsync(ws, 0, 2112, stream);                    // gcnt + ovcnt
    bin_k  <<<NBIN, 512, 0, stream>>>(src, dst, ew, h, Wih, Whh, hb, wfrag,
                                      gcnt, binkey, binwgt,
                                      ovcnt, ov_key, ov_wgt, ov_b);
    sort_k <<<NBKT, 512, 0, stream>>>(binkey, binwgt, gcnt, ovcnt,
                                      ov_key, ov_wgt, ov_b, cursor, deg);
    segsum_k<<<NN / 4, 256, 0, stream>>>(hb, binkey, binwgt, cursor, deg, out);
    gru_k  <<<NBGRU, 256, 0, stream>>>(out, h, wfrag, bih, bhh, out);
}